// Round 1
// 757.644 us; speedup vs baseline: 1.0429x; 1.0429x over previous
//
#include <hip/hip_runtime.h>

// Input order (setup_inputs dict order):
// 0..5: feat00 feat01 feat10 feat11 feat20 feat21  [N,D] fp32
// 6..8: w0 w1 w2  [M,D] fp32
// 9..11: b0 b1 b2 [M,1] fp32
// 12: symbols [N] int
// 13: meta_node_id [N] int
// 14: sym_buf [T] int
// 15: num_masked (scalar) -- K taken from out_size instead (host-known)

typedef float v4f __attribute__((ext_vector_type(4)));

__global__ void count_kernel(const int* __restrict__ symbols,
                             const int* __restrict__ sym_buf,
                             int T, int N, int chunk,
                             int* __restrict__ counts) {
    __shared__ int sbuf[64];
    int Tc = T > 64 ? 64 : T;
    if ((int)threadIdx.x < Tc) sbuf[threadIdx.x] = sym_buf[threadIdx.x];
    __syncthreads();

    int c = blockIdx.x;
    int start = c * chunk;
    int end = min(start + chunk, N);
    int cnt = 0;
    for (int e = start + (int)threadIdx.x; e < end; e += blockDim.x) {
        int s = symbols[e];
        bool hit = false;
        for (int t = 0; t < Tc; ++t) hit = hit || (s == sbuf[t]);
        if (!hit && T > 64)
            for (int t = 64; t < T; ++t) hit = hit || (s == sym_buf[t]);
        cnt += hit ? 1 : 0;
    }
    for (int off = 32; off >= 1; off >>= 1) cnt += __shfl_down(cnt, off);
    __shared__ int lds[4];
    int lane = threadIdx.x & 63, wv = threadIdx.x >> 6;
    if (lane == 0) lds[wv] = cnt;
    __syncthreads();
    if (threadIdx.x == 0) counts[c] = lds[0] + lds[1] + lds[2] + lds[3];
}

// scan_kernel removed: each write block computes its own exclusive prefix
// over the 256 per-chunk counts with a parallel reduction (256 threads ==
// 256 count entries; all loads are L2 hits, ~nothing vs the old 256-long
// serial single-thread latency chain).
__global__ void write_kernel(const int* __restrict__ symbols,
                             const int* __restrict__ sym_buf,
                             int T, int N, int chunk,
                             const int* __restrict__ counts,
                             int* __restrict__ idx, int K) {
    __shared__ int sbuf[64];
    __shared__ int waveTot[4];
    __shared__ int pre[4];
    __shared__ int baseSh;
    int Tc = T > 64 ? 64 : T;
    if ((int)threadIdx.x < Tc) sbuf[threadIdx.x] = sym_buf[threadIdx.x];

    int c = blockIdx.x;
    int lane = threadIdx.x & 63, wv = threadIdx.x >> 6;

    // exclusive prefix sum of counts[0..c-1]; blockDim.x == gridDim.x == 256
    int v = ((int)threadIdx.x < c) ? counts[threadIdx.x] : 0;
    for (int off = 32; off >= 1; off >>= 1) v += __shfl_down(v, off);
    if (lane == 0) pre[wv] = v;
    __syncthreads();
    if (threadIdx.x == 0) baseSh = pre[0] + pre[1] + pre[2] + pre[3];
    __syncthreads();

    int start = c * chunk;
    int end = min(start + chunk, N);
    for (int s = start; s < end; s += blockDim.x) {
        int e = s + (int)threadIdx.x;
        bool hit = false;
        if (e < end) {
            int sym = symbols[e];
            for (int t = 0; t < Tc; ++t) hit = hit || (sym == sbuf[t]);
            if (!hit && T > 64)
                for (int t = 64; t < T; ++t) hit = hit || (sym == sym_buf[t]);
        }
        unsigned long long bal = __ballot(hit);
        int lanePrefix = __popcll(bal & ((1ull << lane) - 1ull));
        int waveCount  = __popcll(bal);
        if (lane == 0) waveTot[wv] = waveCount;
        __syncthreads();
        int wavePrefix = 0;
        for (int w = 0; w < wv; ++w) wavePrefix += waveTot[w];
        int total = waveTot[0] + waveTot[1] + waveTot[2] + waveTot[3];
        if (hit) {
            int pos = baseSh + wavePrefix + lanePrefix;
            if (pos < K) idx[pos] = e;
        }
        __syncthreads();               // everyone done reading baseSh
        if (threadIdx.x == 0) baseSh += total;
        __syncthreads();               // update visible for next iter
    }
}

// One wave per output element k. D assumed multiple of 256 (D=256 here):
// each lane owns 4 consecutive floats -> dwordx4 loads, full 1KB row/wave.
// Feature rows are read exactly once each (idx is strictly increasing,
// unique) -> non-temporal loads so the 307MB feature stream doesn't evict
// the 3MB weight tables (reused K/M ~= 50x each) from L2.
__global__ __launch_bounds__(256) void dot_kernel(
    const float* __restrict__ f00, const float* __restrict__ f01,
    const float* __restrict__ f10, const float* __restrict__ f11,
    const float* __restrict__ f20, const float* __restrict__ f21,
    const float* __restrict__ w0, const float* __restrict__ w1,
    const float* __restrict__ w2,
    const float* __restrict__ b0, const float* __restrict__ b1,
    const float* __restrict__ b2,
    const int* __restrict__ meta, const int* __restrict__ idx,
    float* __restrict__ out, int K, int D) {
    int wv   = threadIdx.x >> 6;
    int lane = threadIdx.x & 63;
    int k = blockIdx.x * 4 + wv;
    if (k >= K) return;
    int id  = idx[k];
    int mid = meta[id];
    float s = 0.0f;
    for (int d0 = lane * 4; d0 < D; d0 += 256) {
        long long fo = (long long)id  * D + d0;
        long long wo = (long long)mid * D + d0;
        v4f W, A, B;
        W = *(const v4f*)(w0 + wo);
        A = __builtin_nontemporal_load((const v4f*)(f00 + fo));
        B = __builtin_nontemporal_load((const v4f*)(f01 + fo));
        s += (A.x + B.x) * W.x + (A.y + B.y) * W.y
           + (A.z + B.z) * W.z + (A.w + B.w) * W.w;
        W = *(const v4f*)(w1 + wo);
        A = __builtin_nontemporal_load((const v4f*)(f10 + fo));
        B = __builtin_nontemporal_load((const v4f*)(f11 + fo));
        s += (A.x + B.x) * W.x + (A.y + B.y) * W.y
           + (A.z + B.z) * W.z + (A.w + B.w) * W.w;
        W = *(const v4f*)(w2 + wo);
        A = __builtin_nontemporal_load((const v4f*)(f20 + fo));
        B = __builtin_nontemporal_load((const v4f*)(f21 + fo));
        s += (A.x + B.x) * W.x + (A.y + B.y) * W.y
           + (A.z + B.z) * W.z + (A.w + B.w) * W.w;
    }
    for (int off = 32; off >= 1; off >>= 1) s += __shfl_down(s, off);
    if (lane == 0) {
        float bias = b0[mid] + b1[mid] + b2[mid];
        out[k] = s * (1.0f / 6.0f) + bias * (1.0f / 3.0f);
    }
}

extern "C" void kernel_launch(void* const* d_in, const int* in_sizes, int n_in,
                              void* d_out, int out_size, void* d_ws, size_t ws_size,
                              hipStream_t stream) {
    const float* f00 = (const float*)d_in[0];
    const float* f01 = (const float*)d_in[1];
    const float* f10 = (const float*)d_in[2];
    const float* f11 = (const float*)d_in[3];
    const float* f20 = (const float*)d_in[4];
    const float* f21 = (const float*)d_in[5];
    const float* w0  = (const float*)d_in[6];
    const float* w1  = (const float*)d_in[7];
    const float* w2  = (const float*)d_in[8];
    const float* b0  = (const float*)d_in[9];
    const float* b1  = (const float*)d_in[10];
    const float* b2  = (const float*)d_in[11];
    const int* symbols = (const int*)d_in[12];
    const int* meta    = (const int*)d_in[13];
    const int* sym_buf = (const int*)d_in[14];

    const int K = out_size;                       // num_masked (static, known to host)
    const int D = in_sizes[6] / in_sizes[9];      // (M*D)/(M*1)
    const int N = in_sizes[0] / D;
    const int T = in_sizes[14];

    int* idx     = (int*)d_ws;                    // K ints
    int* counts  = idx + K;                       // 256 ints

    // nonzero(size=K) zero-pads when fewer than K hits; ws is poisoned 0xAA.
    hipMemsetAsync(idx, 0, (size_t)K * sizeof(int), stream);

    const int B = 256;
    const int chunk = (N + B - 1) / B;
    count_kernel<<<B, 256, 0, stream>>>(symbols, sym_buf, T, N, chunk, counts);
    write_kernel<<<B, 256, 0, stream>>>(symbols, sym_buf, T, N, chunk, counts, idx, K);

    int blocks = (K + 3) / 4;                     // 4 waves/block, 1 wave per k
    dot_kernel<<<blocks, 256, 0, stream>>>(f00, f01, f10, f11, f20, f21,
                                           w0, w1, w2, b0, b1, b2,
                                           meta, idx, (float*)d_out, K, D);
}